// Round 5
// baseline (1742.944 us; speedup 1.0000x reference)
//
#include <hip/hip_runtime.h>
#include <math.h>

// Problem constants (from reference): N_EDGES=500000, N_RELS=256, D=256.
#define D 256
#define R 256
#define DIMC 64       // dims per y-chunk
#define NNODES 200000
#define NB 64                          // node buckets
#define BUCKET ((NNODES + NB - 1) / NB)  // 3125 nodes -> 3.2 MB emb slice

__device__ __forceinline__ float sigmoidf(float x) {
    return 1.0f / (1.0f + expf(-x));
}

// ---- zero workspace (harness poisons ws with 0xAA every call) ----
__global__ void zero_ws(float* ws, int n) {
    int i = blockIdx.x * blockDim.x + threadIdx.x;
    if (i < n) ws[i] = 0.0f;
}

// ---- merged histogram: rel counts (for means) + (side,bucket) counts ----
__global__ __launch_bounds__(256) void hist2_kernel(
    const int* __restrict__ rel, const int* __restrict__ src_nid,
    const int* __restrict__ dst_nid, int E, float* __restrict__ counts,
    int* __restrict__ bcnt) {
    __shared__ int h[R];
    __shared__ int hb[2 * NB];
    const int t = threadIdx.x;
    h[t] = 0;
    if (t < 2 * NB) hb[t] = 0;
    __syncthreads();
    for (int e = blockIdx.x * 256 + t; e < E; e += gridDim.x * 256) {
        atomicAdd(&h[rel[e]], 1);
        atomicAdd(&hb[src_nid[e] / BUCKET], 1);
        atomicAdd(&hb[NB + dst_nid[e] / BUCKET], 1);
    }
    __syncthreads();
    atomicAdd(&counts[t], (float)h[t]);
    if (t < 2 * NB) atomicAdd(&bcnt[t], hb[t]);
}

// ---- tiny prefix: off[2][NB+1] + init padded cursors (stride 64 ints) ----
__global__ void prefix_kernel(const int* __restrict__ bcnt, int* __restrict__ off,
                              int* __restrict__ cur) {
    __shared__ int c[2 * NB];
    const int t = threadIdx.x;
    if (t < 2 * NB) c[t] = bcnt[t];
    __syncthreads();
    if (t == 0) {
        int a = 0;
        for (int b = 0; b < NB; b++) { off[b] = a; cur[b * 64] = a; a += c[b]; }
        off[NB] = a;
        a = 0;
        for (int b = 0; b < NB; b++) {
            off[NB + 1 + b] = a;
            cur[(NB + b) * 64] = a;
            a += c[NB + b];
        }
        off[2 * NB + 1] = a;
    }
}

// ---- bin both sides: key = nid | (rel<<18); cursors padded to 256B ----
__global__ __launch_bounds__(256) void bin_kernel(
    const int* __restrict__ src_nid, const int* __restrict__ dst_nid,
    const int* __restrict__ rel, int E, int* __restrict__ cur,
    unsigned* __restrict__ bin0, unsigned* __restrict__ bin1) {
    for (int e = blockIdx.x * 256 + threadIdx.x; e < E; e += gridDim.x * 256) {
        const unsigned rl = (unsigned)rel[e];
        const int n0 = src_nid[e];
        const int p0 = atomicAdd(&cur[(n0 / BUCKET) * 64], 1);
        bin0[p0] = (unsigned)n0 | (rl << 18);
        const int n1 = dst_nid[e];
        const int p1 = atomicAdd(&cur[(NB + n1 / BUCKET) * 64], 1);
        bin1[p1] = (unsigned)n1 | (rl << 18);
    }
}

// ---- gather + LDS segment sum over XCD-resident buckets ----
// 512 blocks; xcd = g&7 (round-robin heuristic). Each XCD's 64 co-resident
// blocks (8 edge-slices x 4 dim-chunks x 2 sides) sweep the XCD's 8 private
// buckets in lockstep: live emb slice 3.2 MB -> L2-resident -> gathers are
// ~200cyc L2 hits instead of ~500+cyc L2 misses (the R2-R4 invariant wall).
// acc layout [d][r ^ (d&31)]: bank-spread atomics, conflict-free flush.
__global__ __launch_bounds__(1024, 8) void gather_kernel(
    const unsigned* __restrict__ bin0, const unsigned* __restrict__ bin1,
    const int* __restrict__ off, const float* __restrict__ emb,
    float* __restrict__ src_sum, float* __restrict__ dst_sum) {
    __shared__ float acc[R * DIMC];  // 64 KB
    const int tid = threadIdx.x;
    for (int i = tid; i < R * DIMC; i += 1024) acc[i] = 0.0f;
    __syncthreads();

    const int g = blockIdx.x;
    const int xcd = g & 7;
    const int lid = g >> 3;          // 0..63
    const int sl = lid & 7;          // edge-slice within bucket
    const int y = (lid >> 3) & 3;    // dim-chunk
    const int z = lid >> 5;          // side
    const unsigned* bin = z ? bin1 : bin0;
    const int* offs = off + z * (NB + 1);
    float* gsum = z ? dst_sum : src_sum;
    const int dimbase = y * DIMC;

    for (int p = 0; p < NB / 8; p++) {
        const int b = xcd * (NB / 8) + p;
        const int lo = offs[b], hi = offs[b + 1];
        const int cnt = hi - lo;
        const int c0 = lo + ((cnt * sl) >> 3);
        const int c1 = lo + ((cnt * (sl + 1)) >> 3);
        for (int idx = c0 + tid; idx < c1; idx += 1024) {
            const unsigned key = bin[idx];
            const int nid = (int)(key & 0x3FFFFu);
            const int rl = (int)(key >> 18);
            const float4* row = (const float4*)(emb + (size_t)nid * D + dimbase);
#pragma unroll
            for (int c = 0; c < 4; c++) {
                float4 v[4];
#pragma unroll
                for (int k = 0; k < 4; k++) v[k] = row[c * 4 + k];
#pragma unroll
                for (int k = 0; k < 4; k++) {
                    const int d0 = c * 16 + k * 4;
                    atomicAdd(&acc[(d0 + 0) * R + (rl ^ ((d0 + 0) & 31))], v[k].x);
                    atomicAdd(&acc[(d0 + 1) * R + (rl ^ ((d0 + 1) & 31))], v[k].y);
                    atomicAdd(&acc[(d0 + 2) * R + (rl ^ ((d0 + 2) & 31))], v[k].z);
                    atomicAdd(&acc[(d0 + 3) * R + (rl ^ ((d0 + 3) & 31))], v[k].w);
                }
            }
        }
    }
    __syncthreads();
    // flush: global addrs consecutive per 64 lanes; LDS banks all distinct.
    for (int i = tid; i < R * DIMC; i += 1024) {
        const int d = i & (DIMC - 1);
        const int r = i >> 6;
        atomicAdd(&gsum[r * D + dimbase + d], acc[d * R + (r ^ (d & 31))]);
    }
}

// ---- fallback (ws too small): R2 lane-per-edge scatter + rel-only hist ----
__global__ __launch_bounds__(256) void hist_kernel(const int* __restrict__ rel,
                                                   int E,
                                                   float* __restrict__ counts) {
    __shared__ int h[R];
    h[threadIdx.x] = 0;
    __syncthreads();
    for (int e = blockIdx.x * blockDim.x + threadIdx.x; e < E;
         e += gridDim.x * blockDim.x)
        atomicAdd(&h[rel[e]], 1);
    __syncthreads();
    atomicAdd(&counts[threadIdx.x], (float)h[threadIdx.x]);
}

__global__ __launch_bounds__(1024, 8) void scatter_fallback(
    const int* __restrict__ src_nid, const int* __restrict__ dst_nid,
    const int* __restrict__ rel, const float* __restrict__ emb,
    float* __restrict__ src_sum, float* __restrict__ dst_sum, int E, int epb) {
    __shared__ float acc[R * DIMC];
    const int tid = threadIdx.x;
    for (int i = tid; i < R * DIMC; i += 1024) acc[i] = 0.0f;
    __syncthreads();
    const int* nids = blockIdx.z ? dst_nid : src_nid;
    float* gsum = blockIdx.z ? dst_sum : src_sum;
    const int dimbase = blockIdx.y * DIMC;
    const int lane = tid & 63;
    const int wave = tid >> 6;
    const int start = blockIdx.x * epb;
    const int end = (start + epb < E) ? (start + epb) : E;
    for (int base = start + wave * 64; base < end; base += 1024) {
        const int e = base + lane;
        const bool valid = e < end;
        int mynid = 0, myrel = 0;
        if (valid) { mynid = nids[e]; myrel = rel[e]; }
        const float4* row = (const float4*)(emb + (size_t)mynid * D + dimbase);
#pragma unroll
        for (int c = 0; c < 4; c++) {
            float4 v[4];
#pragma unroll
            for (int k = 0; k < 4; k++) v[k] = row[c * 4 + k];
            if (valid) {
#pragma unroll
                for (int k = 0; k < 4; k++) {
                    const int d0 = c * 16 + k * 4;
                    atomicAdd(&acc[(d0 + 0) * R + (myrel ^ ((d0 + 0) & 31))], v[k].x);
                    atomicAdd(&acc[(d0 + 1) * R + (myrel ^ ((d0 + 1) & 31))], v[k].y);
                    atomicAdd(&acc[(d0 + 2) * R + (myrel ^ ((d0 + 2) & 31))], v[k].z);
                    atomicAdd(&acc[(d0 + 3) * R + (myrel ^ ((d0 + 3) & 31))], v[k].w);
                }
            }
        }
    }
    __syncthreads();
    for (int i = tid; i < R * DIMC; i += 1024) {
        const int d = i & (DIMC - 1);
        const int r = i >> 6;
        atomicAdd(&gsum[r * D + dimbase + d], acc[d * R + (r ^ (d & 31))]);
    }
}

// ---- means + GRU cell, one block per relation, 512 threads ----
__global__ __launch_bounds__(512) void gru_kernel(
    const float* __restrict__ src_sum, const float* __restrict__ dst_sum,
    const float* __restrict__ counts, const float* __restrict__ dyn,
    const float* __restrict__ W_ih, const float* __restrict__ W_hh,
    const float* __restrict__ b_ih, const float* __restrict__ b_hh,
    float* __restrict__ out) {
    __shared__ float x2[2][D], h2[2][D];
    const int r = blockIdx.x, t = threadIdx.x;
    const int s = t >> 8;
    const int tt = t & 255;
    const float inv = 1.0f / fmaxf(counts[r], 1.0f);
    float h_old;
    if (s == 0) {
        x2[0][tt] = src_sum[r * D + tt] * inv;
        h_old = dyn[(r * D + tt) * 2 + 0];
        h2[0][tt] = h_old;
    } else {
        x2[1][tt] = dst_sum[r * D + tt] * inv;
        h_old = dyn[(r * D + tt) * 2 + 1];
        h2[1][tt] = h_old;
    }
    __syncthreads();
    const float* xs = x2[s];
    const float* hs = h2[s];

    float gi[3], gh[3];
#pragma unroll
    for (int g = 0; g < 3; g++) {
        const int row = g * D + tt;
        const float4* wi = (const float4*)(W_ih + (size_t)row * D);
        const float4* wh = (const float4*)(W_hh + (size_t)row * D);
        float ai = 0.f, ah = 0.f;
        for (int k = 0; k < D / 4; k++) {
            float4 a = wi[k];
            float4 b = wh[k];
            int k4 = k * 4;
            ai += a.x * xs[k4] + a.y * xs[k4 + 1] + a.z * xs[k4 + 2] + a.w * xs[k4 + 3];
            ah += b.x * hs[k4] + b.y * hs[k4 + 1] + b.z * hs[k4 + 2] + b.w * hs[k4 + 3];
        }
        gi[g] = ai + b_ih[row];
        gh[g] = ah + b_hh[row];
    }
    const float rr = sigmoidf(gi[0] + gh[0]);
    const float zz = sigmoidf(gi[1] + gh[1]);
    const float nn = tanhf(gi[2] + rr * gh[2]);
    const float nh = (1.0f - zz) * nn + zz * h_old;
    out[(r * D + tt) * 2 + s] = nh;
}

extern "C" void kernel_launch(void* const* d_in, const int* in_sizes, int n_in,
                              void* d_out, int out_size, void* d_ws, size_t ws_size,
                              hipStream_t stream) {
    const int* src_nid = (const int*)d_in[0];
    const int* dst_nid = (const int*)d_in[1];
    const int* rel     = (const int*)d_in[2];
    const float* emb   = (const float*)d_in[3];
    const float* dyn   = (const float*)d_in[4];
    const float* W_ih  = (const float*)d_in[5];
    const float* W_hh  = (const float*)d_in[6];
    const float* b_ih  = (const float*)d_in[7];
    const float* b_hh  = (const float*)d_in[8];
    float* out = (float*)d_out;
    const int E = in_sizes[0];

    float* ws      = (float*)d_ws;
    float* src_sum = ws;                         // R*D floats
    float* dst_sum = ws + R * D;                 // R*D floats
    float* counts  = ws + 2 * R * D;             // R floats
    int*   bcnt    = (int*)(counts + R);         // 2*NB ints
    int*   off     = bcnt + 2 * NB;              // 2*(NB+1) ints
    int*   cur     = off + 2 * NB + 2;           // 128*64 ints (256B padded)
    unsigned* bin0 = (unsigned*)(cur + 128 * 64);  // E keys
    unsigned* bin1 = bin0 + E;                     // E keys
    const size_t needed = (size_t)((char*)(bin1 + E) - (char*)ws);

    if (ws_size >= needed) {
        const int nzero = 2 * R * D + R + 2 * NB;  // sums + counts + bcnt
        zero_ws<<<(nzero + 255) / 256, 256, 0, stream>>>(ws, nzero);
        hist2_kernel<<<256, 256, 0, stream>>>(rel, src_nid, dst_nid, E, counts, bcnt);
        prefix_kernel<<<1, 128, 0, stream>>>(bcnt, off, cur);
        bin_kernel<<<512, 256, 0, stream>>>(src_nid, dst_nid, rel, E, cur, bin0, bin1);
        gather_kernel<<<512, 1024, 0, stream>>>(bin0, bin1, off, emb, src_sum, dst_sum);
    } else {
        const int nzero = 2 * R * D + R;
        zero_ws<<<(nzero + 255) / 256, 256, 0, stream>>>(ws, nzero);
        hist_kernel<<<256, 256, 0, stream>>>(rel, E, counts);
        const int chunks = 64;
        const int epb = (E + chunks - 1) / chunks;
        scatter_fallback<<<dim3(chunks, 4, 2), 1024, 0, stream>>>(
            src_nid, dst_nid, rel, emb, src_sum, dst_sum, E, epb);
    }

    gru_kernel<<<R, 512, 0, stream>>>(src_sum, dst_sum, counts, dyn, W_ih, W_hh,
                                      b_ih, b_hh, out);
}